// Round 4
// baseline (620.202 us; speedup 1.0000x reference)
//
#include <hip/hip_runtime.h>
#include <hip/hip_bf16.h>

// B=1, S=256 (attention/LN axis), R=256, C=256, H=8, D=32.
// One workgroup per residue column r; 8 waves = 8 heads; fully fused.
// Round 4: __launch_bounds__(512,2) legalizes 256 VGPRs (round 3 silently
// capped at 128 and spilled ~700 MB of scratch traffic). K^T/V fragments are
// regenerated per j-tile inside the flash loop (16 VGPRs live instead of a
// 128-VGPR persistent array) so peak live regs ~230 -> zero spill.
// Softmax in exp2 domain (log2e folded into Q scale) + deferred-rescale
// (skip corr-broadcast when tile max grows < 8 in log2 domain).

using f32x4  = __attribute__((ext_vector_type(4))) float;
using bf16x8 = __attribute__((ext_vector_type(8))) short;

struct U4x { unsigned a0, a1, a2, a3; };
static_assert(sizeof(U4x) == sizeof(bf16x8), "frag size");

__device__ __forceinline__ f32x4 mfma16(bf16x8 a, bf16x8 b, f32x4 c){
  return __builtin_amdgcn_mfma_f32_16x16x32_bf16(a, b, c, 0, 0, 0);
}
// f32 -> bf16 RNE, finite inputs only.
__device__ __forceinline__ unsigned f2bf(float f){
  unsigned u = __builtin_bit_cast(unsigned, f);
  u += 0x7fffu + ((u >> 16) & 1u);
  return u >> 16;
}
__device__ __forceinline__ unsigned pk2(float lo, float hi){
  return f2bf(lo) | (f2bf(hi) << 16);
}
__device__ __forceinline__ bf16x8 mk_frag(unsigned a0, unsigned a1, unsigned a2, unsigned a3){
  U4x t{a0, a1, a2, a3};
  return __builtin_bit_cast(bf16x8, t);
}
__device__ __forceinline__ float sigm(float x){ return 1.f / (1.f + __expf(-x)); }

// Swizzled byte address in the [256 rows][256 bf16] LDS tile (row stride 512B).
__device__ __forceinline__ int xaddr(int row, int cbyte){
  return (row << 9) + (cbyte ^ ((row & 15) << 4));
}
__device__ __forceinline__ bf16x8 lds_frag(const char* sm, int row, int cshort){
  return *(const bf16x8*)(sm + xaddr(row, cshort * 2));
}
__device__ __forceinline__ bf16x8 ldg_frag(const short* base, int row, int cshort){
  return *(const bf16x8*)(base + row * 256 + cshort);
}

// ---------------- prep: transpose + bf16-convert the 5 weight matrices -----
// ws (shorts): WqT[256][256], WkT, WvT, WgT  (T[n][c] = W[c][n], n = h*32+d)
//              WoT[256][256]                 (WoT[c][hd] = Wo[hd][c])
__global__ __launch_bounds__(256) void prep_weights(
    const float* __restrict__ Wq, const float* __restrict__ Wk,
    const float* __restrict__ Wv, const float* __restrict__ Wg,
    const float* __restrict__ Wo, short* __restrict__ ws)
{
  const int n = blockIdx.x, t = threadIdx.x;
  ws[0*65536 + n*256 + t] = (short)f2bf(Wq[t*256 + n]);
  ws[1*65536 + n*256 + t] = (short)f2bf(Wk[t*256 + n]);
  ws[2*65536 + n*256 + t] = (short)f2bf(Wv[t*256 + n]);
  ws[3*65536 + n*256 + t] = (short)f2bf(Wg[t*256 + n]);
  ws[4*65536 + n*256 + t] = (short)f2bf(Wo[t*256 + n]);
}

// ---------------- per-half attention (queries [IB, IB+128)) ----------------
template<int IB>
__device__ __forceinline__ void attn_half(
    const char* sm, const short* WqT, const short* WkT,
    const short* WvT, const short* WgT,
    int hbase, int g, int c15, float bg0, float bg1,
    unsigned (&go0)[8][2], unsigned (&go1)[8][2])
{
  // 1/sqrt(32) * log2(e): softmax runs in exp2 domain.
  const float scl = 0.17677669529663687f * 1.4426950408889634f;
  // A) Q^T = WqT @ X^T, weight frags hoisted per d-row (8 live at a time)
  unsigned qTa[8][2], qTb[8][2];
  #pragma unroll
  for (int dr = 0; dr < 2; dr++){
    bf16x8 wq[8];
    #pragma unroll
    for (int kk = 0; kk < 8; kk++) wq[kk] = ldg_frag(WqT, hbase + 16*dr + c15, 32*kk + 8*g);
    #pragma unroll
    for (int nt = 0; nt < 8; nt++){
      f32x4 a{0,0,0,0};
      #pragma unroll
      for (int kk = 0; kk < 8; kk++)
        a = mfma16(wq[kk], lds_frag(sm, IB + nt*16 + c15, 32*kk + 8*g), a);
      if (dr == 0){ qTa[nt][0] = pk2(a.x*scl, a.y*scl); qTa[nt][1] = pk2(a.z*scl, a.w*scl); }
      else        { qTb[nt][0] = pk2(a.x*scl, a.y*scl); qTb[nt][1] = pk2(a.z*scl, a.w*scl); }
    }
  }

  // B) flash over j-tiles of 32: regen K^T/V per tile, S^T = K x Q^T,
  //    online softmax (exp2 domain, deferred rescale), PV.
  float m_[8], l_[8];
  f32x4 o_[8][2];
  #pragma unroll
  for (int i2 = 0; i2 < 8; i2++){
    m_[i2] = -1e30f; l_[i2] = 0.f;
    o_[i2][0] = f32x4{0,0,0,0}; o_[i2][1] = f32x4{0,0,0,0};
  }
  #pragma unroll 1
  for (int jt = 0; jt < 8; jt++){
    const int jb = jt * 32;
    // -- regen K^T/V fragments for this j-tile (weights L2-hot) --
    f32x4 kt00{0,0,0,0}, kt01{0,0,0,0}, kt10{0,0,0,0}, kt11{0,0,0,0};
    f32x4 va00{0,0,0,0}, va01{0,0,0,0}, va10{0,0,0,0}, va11{0,0,0,0};
    #pragma unroll
    for (int kk = 0; kk < 8; kk++){
      const int cs = 32*kk + 8*g;
      bf16x8 wk0 = ldg_frag(WkT, hbase + c15,      cs);
      bf16x8 wk1 = ldg_frag(WkT, hbase + 16 + c15, cs);
      bf16x8 wv0 = ldg_frag(WvT, hbase + c15,      cs);
      bf16x8 wv1 = ldg_frag(WvT, hbase + 16 + c15, cs);
      bf16x8 bx0 = lds_frag(sm, jb + c15,      cs);
      bf16x8 bx1 = lds_frag(sm, jb + 16 + c15, cs);
      kt00 = mfma16(wk0, bx0, kt00);   // K^T[d 0:16 ][j 0:16 ]
      kt01 = mfma16(wk0, bx1, kt01);   // K^T[d 0:16 ][j 16:32]
      kt10 = mfma16(wk1, bx0, kt10);   // K^T[d 16:32][j 0:16 ]
      kt11 = mfma16(wk1, bx1, kt11);   // K^T[d 16:32][j 16:32]
      va00 = mfma16(bx0, wv0, va00);   // V[j 0:16 ][d 0:16 ]
      va01 = mfma16(bx0, wv1, va01);   // V[j 0:16 ][d 16:32]
      va10 = mfma16(bx1, wv0, va10);   // V[j 16:32][d 0:16 ]
      va11 = mfma16(bx1, wv1, va11);   // V[j 16:32][d 16:32]
    }
    const bf16x8 kf0 = mk_frag(pk2(kt00.x,kt00.y), pk2(kt00.z,kt00.w),
                               pk2(kt10.x,kt10.y), pk2(kt10.z,kt10.w));
    const bf16x8 kf1 = mk_frag(pk2(kt01.x,kt01.y), pk2(kt01.z,kt01.w),
                               pk2(kt11.x,kt11.y), pk2(kt11.z,kt11.w));
    const bf16x8 vf0 = mk_frag(pk2(va00.x,va00.y), pk2(va00.z,va00.w),
                               pk2(va10.x,va10.y), pk2(va10.z,va10.w));
    const bf16x8 vf1 = mk_frag(pk2(va01.x,va01.y), pk2(va01.z,va01.w),
                               pk2(va11.x,va11.y), pk2(va11.z,va11.w));
    // -- flash inner loop over the 8 i-tiles of this half --
    #pragma unroll
    for (int it = 0; it < 8; it++){
      bf16x8 bS = mk_frag(qTa[it][0], qTa[it][1], qTb[it][0], qTb[it][1]);
      f32x4 z{0,0,0,0};
      f32x4 s0 = mfma16(kf0, bS, z);   // S^T: lane holds S[i=c15][j=jb+4g+jj]
      f32x4 s1 = mfma16(kf1, bS, z);   //      S[i=c15][j=jb+16+4g+jj]
      float pm = fmaxf(fmaxf(fmaxf(s0.x,s0.y), fmaxf(s0.z,s0.w)),
                       fmaxf(fmaxf(s1.x,s1.y), fmaxf(s1.z,s1.w)));
      pm = fmaxf(pm, __shfl_xor(pm, 16));
      pm = fmaxf(pm, __shfl_xor(pm, 32));
      const bool skip = __all(pm <= m_[it] + 8.f) != 0;   // wave-uniform
      const float mnew = skip ? m_[it] : fmaxf(m_[it], pm);
      float e0=exp2f(s0.x-mnew), e1=exp2f(s0.y-mnew), e2=exp2f(s0.z-mnew), e3=exp2f(s0.w-mnew);
      float e4=exp2f(s1.x-mnew), e5=exp2f(s1.y-mnew), e6=exp2f(s1.z-mnew), e7=exp2f(s1.w-mnew);
      float rs = ((e0+e1)+(e2+e3)) + ((e4+e5)+(e6+e7));
      rs += __shfl_xor(rs, 16); rs += __shfl_xor(rs, 32);
      if (skip){
        l_[it] += rs;
      } else {
        const float corr = exp2f(m_[it] - mnew);
        l_[it] = l_[it] * corr + rs;
        m_[it] = mnew;
        #pragma unroll
        for (int jj = 0; jj < 4; jj++){
          const float cj = __shfl(corr, 4*g + jj);   // O-frag row i = 4g+jj
          o_[it][0][jj] *= cj;
          o_[it][1][jj] *= cj;
        }
      }
      bf16x8 aP = mk_frag(pk2(e0,e1), pk2(e2,e3), pk2(e4,e5), pk2(e6,e7));
      o_[it][0] = mfma16(aP, vf0, o_[it][0]);
      o_[it][1] = mfma16(aP, vf1, o_[it][1]);
    }
  }

  // C) G = sigmoid(X@Wg + bg) (f32), normalize O, gate, pack bf16
  #pragma unroll
  for (int dr = 0; dr < 2; dr++){
    bf16x8 wg[8];
    #pragma unroll
    for (int kk = 0; kk < 8; kk++) wg[kk] = ldg_frag(WgT, hbase + 16*dr + c15, 32*kk + 8*g);
    const float bgd = dr ? bg1 : bg0;
    #pragma unroll
    for (int nt = 0; nt < 8; nt++){
      f32x4 a{0,0,0,0};
      #pragma unroll
      for (int kk = 0; kk < 8; kk++)
        a = mfma16(lds_frag(sm, IB + nt*16 + c15, 32*kk + 8*g), wg[kk], a);
      float inv[4];
      #pragma unroll
      for (int jj = 0; jj < 4; jj++) inv[jj] = 1.f / __shfl(l_[nt], 4*g + jj);
      const float ga0 = sigm(a.x + bgd), ga1 = sigm(a.y + bgd);
      const float ga2 = sigm(a.z + bgd), ga3 = sigm(a.w + bgd);
      const f32x4 ov = o_[nt][dr];
      const unsigned w0 = pk2(ov[0]*inv[0]*ga0, ov[1]*inv[1]*ga1);
      const unsigned w1 = pk2(ov[2]*inv[2]*ga2, ov[3]*inv[3]*ga3);
      if (dr == 0){ go0[nt][0] = w0; go0[nt][1] = w1; }
      else        { go1[nt][0] = w0; go1[nt][1] = w1; }
    }
  }
}

__device__ __forceinline__ void store_go(char* sm, int i0, int hd, unsigned v0, unsigned v1){
  *(short*)(sm + xaddr(i0 + 0, hd * 2)) = (short)(v0 & 0xffffu);
  *(short*)(sm + xaddr(i0 + 1, hd * 2)) = (short)(v0 >> 16);
  *(short*)(sm + xaddr(i0 + 2, hd * 2)) = (short)(v1 & 0xffffu);
  *(short*)(sm + xaddr(i0 + 3, hd * 2)) = (short)(v1 >> 16);
}

// ---------------- main fused kernel ----------------------------------------
__global__ __launch_bounds__(512, 2) void msa_attn(
    const float* __restrict__ msa, const float* __restrict__ lnw,
    const float* __restrict__ lnb, const float* __restrict__ bg,
    const float* __restrict__ bo,  const short* __restrict__ wsW,
    float* __restrict__ out)
{
  extern __shared__ __align__(16) char sm[];   // [0,131072): x / GO tile (bf16, swizzled)
  float* muA = (float*)(sm + 131072);          // 256 f32
  float* rsA = muA + 256;                      // 256 f32

  const int r   = blockIdx.x;
  const int tid = threadIdx.x;
  const float* msa_r = msa + r * 256;          // msa[s][r][c] = msa_r[s*65536 + c]

  // ---- phase 1a: LN stats over s for each c ----
  {
    float s0 = 0.f, s1 = 0.f;
    const int c = tid & 255, sh = tid >> 8;
    const float* p = msa_r + (sh * 128) * 65536 + c;
    #pragma unroll 8
    for (int i = 0; i < 128; i++){ float v = p[i * 65536]; s0 += v; s1 += v * v; }
    float* sb = (float*)sm;                    // transient, overlaps x tile
    sb[tid] = s0; sb[512 + tid] = s1;
    __syncthreads();
    if (tid < 256){
      float tot = sb[tid] + sb[256 + tid];
      float sq  = sb[512 + tid] + sb[768 + tid];
      float mu  = tot * (1.f / 256.f);
      float var = fmaxf(sq * (1.f / 256.f) - mu * mu, 0.f);
      muA[tid] = mu; rsA[tid] = rsqrtf(var + 1e-5f);
    }
    __syncthreads();
  }
  // ---- phase 1b: normalized x tile (bf16, swizzled) ----
  {
    const int c0 = (tid & 31) * 8;
    float mu0[8], rs0[8];
    #pragma unroll
    for (int k = 0; k < 8; k++){ mu0[k] = muA[c0 + k]; rs0[k] = rsA[c0 + k]; }
    for (int itr = 0; itr < 16; itr++){
      const int s = itr * 16 + (tid >> 5);
      const float w = lnw[s], b = lnb[s];
      const float* rp = msa_r + s * 65536 + c0;
      f32x4 v0 = *(const f32x4*)rp;
      f32x4 v1 = *(const f32x4*)(rp + 4);
      U4x q{pk2((v0.x-mu0[0])*rs0[0]*w+b, (v0.y-mu0[1])*rs0[1]*w+b),
            pk2((v0.z-mu0[2])*rs0[2]*w+b, (v0.w-mu0[3])*rs0[3]*w+b),
            pk2((v1.x-mu0[4])*rs0[4]*w+b, (v1.y-mu0[5])*rs0[5]*w+b),
            pk2((v1.z-mu0[6])*rs0[6]*w+b, (v1.w-mu0[7])*rs0[7]*w+b)};
      *(U4x*)(sm + xaddr(s, c0 * 2)) = q;
    }
    __syncthreads();
  }

  // ---- phase 2: per-wave (= per-head) attention ----
  const int wid  = tid >> 6;                   // head
  const int lane = tid & 63;
  const int g = lane >> 4, c15 = lane & 15;
  const short* WqT = wsW;
  const short* WkT = wsW + 65536;
  const short* WvT = wsW + 2 * 65536;
  const short* WgT = wsW + 3 * 65536;
  const short* WoT = wsW + 4 * 65536;
  const int hbase = wid * 32;
  const float bg0 = bg[hbase + c15], bg1 = bg[hbase + 16 + c15];

  unsigned g00[8][2], g01[8][2], g10[8][2], g11[8][2];
  attn_half<0>  (sm, WqT, WkT, WvT, WgT, hbase, g, c15, bg0, bg1, g00, g01);
  attn_half<128>(sm, WqT, WkT, WvT, WgT, hbase, g, c15, bg0, bg1, g10, g11);

  __syncthreads();   // x tile dead; reuse LDS for GO [i][hd], same swizzle
  #pragma unroll
  for (int it = 0; it < 8; it++){
    const int ia = it * 16 + g * 4, ib = 128 + it * 16 + g * 4;
    store_go(sm, ia, hbase + c15,      g00[it][0], g00[it][1]);
    store_go(sm, ia, hbase + 16 + c15, g01[it][0], g01[it][1]);
    store_go(sm, ib, hbase + c15,      g10[it][0], g10[it][1]);
    store_go(sm, ib, hbase + 16 + c15, g11[it][0], g11[it][1]);
  }
  __syncthreads();

  // ---- phase 3: out = GO @ Wo + bo; store out[s][r][c] ----
  #pragma unroll
  for (int t2 = 0; t2 < 2; t2++){
    const int it = wid * 2 + t2;               // i-tile 0..15
    bf16x8 aGO[8];
    #pragma unroll
    for (int kk = 0; kk < 8; kk++) aGO[kk] = lds_frag(sm, it * 16 + c15, 32 * kk + 8 * g);
    #pragma unroll 2
    for (int ct = 0; ct < 16; ct++){
      f32x4 acc{0,0,0,0};
      #pragma unroll
      for (int kk = 0; kk < 8; kk++)
        acc = mfma16(aGO[kk], ldg_frag(WoT, ct * 16 + c15, 32 * kk + 8 * g), acc);
      const float bov = bo[ct * 16 + c15];
      const int i0 = it * 16 + g * 4;
      const int cc = ct * 16 + c15;
      out[(i0 + 0) * 65536 + r * 256 + cc] = acc.x + bov;
      out[(i0 + 1) * 65536 + r * 256 + cc] = acc.y + bov;
      out[(i0 + 2) * 65536 + r * 256 + cc] = acc.z + bov;
      out[(i0 + 3) * 65536 + r * 256 + cc] = acc.w + bov;
    }
  }
}

extern "C" void kernel_launch(void* const* d_in, const int* in_sizes, int n_in,
                              void* d_out, int out_size, void* d_ws, size_t ws_size,
                              hipStream_t stream)
{
  (void)in_sizes; (void)n_in; (void)out_size; (void)ws_size;
  const float* msa = (const float*)d_in[0];
  const float* lnw = (const float*)d_in[1];
  const float* lnb = (const float*)d_in[2];
  const float* Wq  = (const float*)d_in[3];
  const float* Wk  = (const float*)d_in[4];
  const float* Wv  = (const float*)d_in[5];
  const float* Wg  = (const float*)d_in[6];
  const float* bg  = (const float*)d_in[7];
  const float* Wo  = (const float*)d_in[8];
  const float* bo  = (const float*)d_in[9];
  short* ws = (short*)d_ws;                    // 5*65536*2 = 640 KB scratch

  prep_weights<<<256, 256, 0, stream>>>(Wq, Wk, Wv, Wg, Wo, ws);
  msa_attn<<<256, 512, 133120, stream>>>(msa, lnw, lnb, bg, bo, ws, (float*)d_out);
}

// Round 5
// 251.535 us; speedup vs baseline: 2.4657x; 2.4657x over previous
//
#include <hip/hip_runtime.h>
#include <hip/hip_bf16.h>

// B=1, S=256 (attention/LN axis), R=256, C=256, H=8, D=32.
// Round 5: amdgpu_waves_per_eu(2,2) unlocks 256 VGPRs/wave (launch_bounds'
// 2nd arg empirically left the cap at 128 -> massive scratch spill in r3/r4).
// K^T/V bf16 fragments persist in registers (128 VGPRs), queries processed in
// 4 chunks of 64 (small o_/qT state), gated output scattered to global ws and
// projected by a separate high-occupancy GEMM kernel. Fallback to the round-4
// fused kernel if ws is too small for the 34 MB GO buffer.

using f32x4  = __attribute__((ext_vector_type(4))) float;
using bf16x8 = __attribute__((ext_vector_type(8))) short;

struct U4x { unsigned a0, a1, a2, a3; };
static_assert(sizeof(U4x) == sizeof(bf16x8), "frag size");

__device__ __forceinline__ f32x4 mfma16(bf16x8 a, bf16x8 b, f32x4 c){
  return __builtin_amdgcn_mfma_f32_16x16x32_bf16(a, b, c, 0, 0, 0);
}
// f32 -> bf16 RNE, finite inputs only.
__device__ __forceinline__ unsigned f2bf(float f){
  unsigned u = __builtin_bit_cast(unsigned, f);
  u += 0x7fffu + ((u >> 16) & 1u);
  return u >> 16;
}
__device__ __forceinline__ unsigned pk2(float lo, float hi){
  return f2bf(lo) | (f2bf(hi) << 16);
}
__device__ __forceinline__ bf16x8 mk_frag(unsigned a0, unsigned a1, unsigned a2, unsigned a3){
  U4x t{a0, a1, a2, a3};
  return __builtin_bit_cast(bf16x8, t);
}
__device__ __forceinline__ float sigm(float x){ return 1.f / (1.f + __expf(-x)); }

// Swizzled byte address in the [256 rows][256 bf16] LDS tile (row stride 512B).
__device__ __forceinline__ int xaddr(int row, int cbyte){
  return (row << 9) + (cbyte ^ ((row & 15) << 4));
}
__device__ __forceinline__ bf16x8 lds_frag(const char* sm, int row, int cshort){
  return *(const bf16x8*)(sm + xaddr(row, cshort * 2));
}
__device__ __forceinline__ bf16x8 ldg_frag(const short* base, int row, int cshort){
  return *(const bf16x8*)(base + row * 256 + cshort);
}

// ---------------- prep: transpose + bf16-convert the 5 weight matrices -----
__global__ __launch_bounds__(256) void prep_weights(
    const float* __restrict__ Wq, const float* __restrict__ Wk,
    const float* __restrict__ Wv, const float* __restrict__ Wg,
    const float* __restrict__ Wo, short* __restrict__ ws)
{
  const int n = blockIdx.x, t = threadIdx.x;
  ws[0*65536 + n*256 + t] = (short)f2bf(Wq[t*256 + n]);
  ws[1*65536 + n*256 + t] = (short)f2bf(Wk[t*256 + n]);
  ws[2*65536 + n*256 + t] = (short)f2bf(Wv[t*256 + n]);
  ws[3*65536 + n*256 + t] = (short)f2bf(Wg[t*256 + n]);
  ws[4*65536 + n*256 + t] = (short)f2bf(Wo[t*256 + n]);
}

// ---------------- phase 1 (shared): LN stats + normalized x tile -----------
__device__ __forceinline__ void build_x_tile(
    char* sm, const float* msa_r, const float* lnw, const float* lnb, int tid)
{
  float* muA = (float*)(sm + 131072);
  float* rsA = muA + 256;
  {
    float s0 = 0.f, s1 = 0.f;
    const int c = tid & 255, sh = tid >> 8;
    const float* p = msa_r + (sh * 128) * 65536 + c;
    #pragma unroll 8
    for (int i = 0; i < 128; i++){ float v = p[i * 65536]; s0 += v; s1 += v * v; }
    float* sb = (float*)sm;
    sb[tid] = s0; sb[512 + tid] = s1;
    __syncthreads();
    if (tid < 256){
      float tot = sb[tid] + sb[256 + tid];
      float sq  = sb[512 + tid] + sb[768 + tid];
      float mu  = tot * (1.f / 256.f);
      float var = fmaxf(sq * (1.f / 256.f) - mu * mu, 0.f);
      muA[tid] = mu; rsA[tid] = rsqrtf(var + 1e-5f);
    }
    __syncthreads();
  }
  {
    const int c0 = (tid & 31) * 8;
    float mu0[8], rs0[8];
    #pragma unroll
    for (int k = 0; k < 8; k++){ mu0[k] = muA[c0 + k]; rs0[k] = rsA[c0 + k]; }
    for (int itr = 0; itr < 16; itr++){
      const int s = itr * 16 + (tid >> 5);
      const float w = lnw[s], b = lnb[s];
      const float* rp = msa_r + s * 65536 + c0;
      f32x4 v0 = *(const f32x4*)rp;
      f32x4 v1 = *(const f32x4*)(rp + 4);
      U4x q{pk2((v0.x-mu0[0])*rs0[0]*w+b, (v0.y-mu0[1])*rs0[1]*w+b),
            pk2((v0.z-mu0[2])*rs0[2]*w+b, (v0.w-mu0[3])*rs0[3]*w+b),
            pk2((v1.x-mu0[4])*rs0[4]*w+b, (v1.y-mu0[5])*rs0[5]*w+b),
            pk2((v1.z-mu0[6])*rs0[6]*w+b, (v1.w-mu0[7])*rs0[7]*w+b)};
      *(U4x*)(sm + xaddr(s, c0 * 2)) = q;
    }
    __syncthreads();
  }
}

// ---------------- main fused kernel (GO -> global scratch) -----------------
__global__ __launch_bounds__(512) __attribute__((amdgpu_waves_per_eu(2, 2)))
void msa_attn_go(
    const float* __restrict__ msa, const float* __restrict__ lnw,
    const float* __restrict__ lnb, const float* __restrict__ bg,
    const short* __restrict__ wsW, short* __restrict__ go)
{
  extern __shared__ __align__(16) char sm[];   // x tile (bf16, swizzled) + stats
  const int r   = blockIdx.x;
  const int tid = threadIdx.x;
  const float* msa_r = msa + r * 256;

  build_x_tile(sm, msa_r, lnw, lnb, tid);

  const int wid  = tid >> 6;                   // head
  const int lane = tid & 63;
  const int g = lane >> 4, c15 = lane & 15;
  const short* WqT = wsW;
  const short* WkT = wsW + 65536;
  const short* WvT = wsW + 2 * 65536;
  const short* WgT = wsW + 3 * 65536;
  const int hbase = wid * 32;
  const float bg0 = bg[hbase + c15], bg1 = bg[hbase + 16 + c15];
  // 1/sqrt(32) * log2(e): softmax in exp2 domain.
  const float scl = 0.17677669529663687f * 1.4426950408889634f;

  // ---- KV-gen ONCE into registers (persist for all 4 query chunks) ----
  bf16x8 kfr[8][2], vfr[8][2];
  #pragma unroll
  for (int ch = 0; ch < 2; ch++){              // j-tile chunks of 4
    f32x4 kt[4][2][2], va[4][2][2];
    #pragma unroll
    for (int a = 0; a < 4; a++)
      #pragma unroll
      for (int b = 0; b < 2; b++)
        #pragma unroll
        for (int d = 0; d < 2; d++){ kt[a][b][d] = f32x4{0,0,0,0}; va[a][b][d] = f32x4{0,0,0,0}; }
    #pragma unroll
    for (int kk = 0; kk < 8; kk++){
      const int cs = 32*kk + 8*g;
      bf16x8 wk0 = ldg_frag(WkT, hbase + c15,      cs);
      bf16x8 wk1 = ldg_frag(WkT, hbase + 16 + c15, cs);
      bf16x8 wv0 = ldg_frag(WvT, hbase + c15,      cs);
      bf16x8 wv1 = ldg_frag(WvT, hbase + 16 + c15, cs);
      #pragma unroll
      for (int j4 = 0; j4 < 4; j4++){
        const int jb = (ch*4 + j4) * 32;
        bf16x8 bx0 = lds_frag(sm, jb + c15,      cs);
        bf16x8 bx1 = lds_frag(sm, jb + 16 + c15, cs);
        kt[j4][0][0] = mfma16(wk0, bx0, kt[j4][0][0]);
        kt[j4][0][1] = mfma16(wk0, bx1, kt[j4][0][1]);
        kt[j4][1][0] = mfma16(wk1, bx0, kt[j4][1][0]);
        kt[j4][1][1] = mfma16(wk1, bx1, kt[j4][1][1]);
        va[j4][0][0] = mfma16(bx0, wv0, va[j4][0][0]);
        va[j4][0][1] = mfma16(bx0, wv1, va[j4][0][1]);
        va[j4][1][0] = mfma16(bx1, wv0, va[j4][1][0]);
        va[j4][1][1] = mfma16(bx1, wv1, va[j4][1][1]);
      }
    }
    #pragma unroll
    for (int j4 = 0; j4 < 4; j4++){
      const int jt = ch*4 + j4;
      kfr[jt][0] = mk_frag(pk2(kt[j4][0][0].x,kt[j4][0][0].y), pk2(kt[j4][0][0].z,kt[j4][0][0].w),
                           pk2(kt[j4][1][0].x,kt[j4][1][0].y), pk2(kt[j4][1][0].z,kt[j4][1][0].w));
      kfr[jt][1] = mk_frag(pk2(kt[j4][0][1].x,kt[j4][0][1].y), pk2(kt[j4][0][1].z,kt[j4][0][1].w),
                           pk2(kt[j4][1][1].x,kt[j4][1][1].y), pk2(kt[j4][1][1].z,kt[j4][1][1].w));
      vfr[jt][0] = mk_frag(pk2(va[j4][0][0].x,va[j4][0][0].y), pk2(va[j4][0][0].z,va[j4][0][0].w),
                           pk2(va[j4][1][0].x,va[j4][1][0].y), pk2(va[j4][1][0].z,va[j4][1][0].w));
      vfr[jt][1] = mk_frag(pk2(va[j4][0][1].x,va[j4][0][1].y), pk2(va[j4][0][1].z,va[j4][0][1].w),
                           pk2(va[j4][1][1].x,va[j4][1][1].y), pk2(va[j4][1][1].z,va[j4][1][1].w));
    }
  }

  // ---- 4 query chunks of 64 rows ----
  short* goR = go + r * 65536;
  #pragma unroll 1
  for (int chq = 0; chq < 4; chq++){
    const int ib = chq * 64;
    // A) Q^T for this chunk
    unsigned qTa[4][2], qTb[4][2];
    #pragma unroll
    for (int dr = 0; dr < 2; dr++){
      bf16x8 wq[8];
      #pragma unroll
      for (int kk = 0; kk < 8; kk++) wq[kk] = ldg_frag(WqT, hbase + 16*dr + c15, 32*kk + 8*g);
      #pragma unroll
      for (int nt = 0; nt < 4; nt++){
        f32x4 a{0,0,0,0};
        #pragma unroll
        for (int kk = 0; kk < 8; kk++)
          a = mfma16(wq[kk], lds_frag(sm, ib + nt*16 + c15, 32*kk + 8*g), a);
        if (dr == 0){ qTa[nt][0] = pk2(a.x*scl, a.y*scl); qTa[nt][1] = pk2(a.z*scl, a.w*scl); }
        else        { qTb[nt][0] = pk2(a.x*scl, a.y*scl); qTb[nt][1] = pk2(a.z*scl, a.w*scl); }
      }
    }
    // B) flash over j-tiles: pure-register (KV resident)
    float m_[4], l_[4];
    f32x4 o_[4][2];
    #pragma unroll
    for (int i2 = 0; i2 < 4; i2++){
      m_[i2] = -1e30f; l_[i2] = 0.f;
      o_[i2][0] = f32x4{0,0,0,0}; o_[i2][1] = f32x4{0,0,0,0};
    }
    #pragma unroll
    for (int jt = 0; jt < 8; jt++){
      #pragma unroll
      for (int it = 0; it < 4; it++){
        bf16x8 bS = mk_frag(qTa[it][0], qTa[it][1], qTb[it][0], qTb[it][1]);
        f32x4 z{0,0,0,0};
        f32x4 s0 = mfma16(kfr[jt][0], bS, z);
        f32x4 s1 = mfma16(kfr[jt][1], bS, z);
        float pm = fmaxf(fmaxf(fmaxf(s0.x,s0.y), fmaxf(s0.z,s0.w)),
                         fmaxf(fmaxf(s1.x,s1.y), fmaxf(s1.z,s1.w)));
        pm = fmaxf(pm, __shfl_xor(pm, 16));
        pm = fmaxf(pm, __shfl_xor(pm, 32));
        const bool skip = __all(pm <= m_[it] + 8.f) != 0;   // wave-uniform
        const float mnew = skip ? m_[it] : fmaxf(m_[it], pm);
        float e0=exp2f(s0.x-mnew), e1=exp2f(s0.y-mnew), e2=exp2f(s0.z-mnew), e3=exp2f(s0.w-mnew);
        float e4=exp2f(s1.x-mnew), e5=exp2f(s1.y-mnew), e6=exp2f(s1.z-mnew), e7=exp2f(s1.w-mnew);
        float rs = ((e0+e1)+(e2+e3)) + ((e4+e5)+(e6+e7));
        rs += __shfl_xor(rs, 16); rs += __shfl_xor(rs, 32);
        if (skip){
          l_[it] += rs;
        } else {
          const float corr = exp2f(m_[it] - mnew);
          l_[it] = l_[it] * corr + rs;
          m_[it] = mnew;
          #pragma unroll
          for (int jj = 0; jj < 4; jj++){
            const float cj = __shfl(corr, 4*g + jj);
            o_[it][0][jj] *= cj;
            o_[it][1][jj] *= cj;
          }
        }
        bf16x8 aP = mk_frag(pk2(e0,e1), pk2(e2,e3), pk2(e4,e5), pk2(e6,e7));
        o_[it][0] = mfma16(aP, vfr[jt][0], o_[it][0]);
        o_[it][1] = mfma16(aP, vfr[jt][1], o_[it][1]);
      }
    }
    // C) G = sigmoid(X@Wg+bg), normalize, gate, scatter GO (bf16) to global
    #pragma unroll
    for (int dr = 0; dr < 2; dr++){
      const float bgd = dr ? bg1 : bg0;
      #pragma unroll
      for (int nt = 0; nt < 4; nt++){
        f32x4 a{0,0,0,0};
        #pragma unroll
        for (int kk = 0; kk < 8; kk++)
          a = mfma16(lds_frag(sm, ib + nt*16 + c15, 32*kk + 8*g),
                     ldg_frag(WgT, hbase + 16*dr + c15, 32*kk + 8*g), a);
        float inv[4];
        #pragma unroll
        for (int jj = 0; jj < 4; jj++) inv[jj] = 1.f / __shfl(l_[nt], 4*g + jj);
        const float ga0 = sigm(a.x + bgd), ga1 = sigm(a.y + bgd);
        const float ga2 = sigm(a.z + bgd), ga3 = sigm(a.w + bgd);
        const f32x4 ov = o_[nt][dr];
        const unsigned w0 = pk2(ov[0]*inv[0]*ga0, ov[1]*inv[1]*ga1);
        const unsigned w1 = pk2(ov[2]*inv[2]*ga2, ov[3]*inv[3]*ga3);
        short* gp = goR + (ib + nt*16 + 4*g) * 256 + hbase + 16*dr + c15;
        gp[0]   = (short)(w0 & 0xffffu);
        gp[256] = (short)(w0 >> 16);
        gp[512] = (short)(w1 & 0xffffu);
        gp[768] = (short)(w1 >> 16);
      }
    }
  }
}

// ---------------- output projection: out = GO @ Wo + bo --------------------
__global__ __launch_bounds__(256) void out_proj(
    const short* __restrict__ go, const short* __restrict__ WoT,
    const float* __restrict__ bo, float* __restrict__ out)
{
  const int blk = blockIdx.x;            // 0..1023
  const int r = blk >> 2, chunk = blk & 3;
  const int wid = threadIdx.x >> 6, lane = threadIdx.x & 63;
  const int g = lane >> 4, c15 = lane & 15;
  const int it = chunk * 4 + wid;        // i-tile 0..15
  const short* goR = go + r * 65536;

  bf16x8 aGO[8];
  #pragma unroll
  for (int kk = 0; kk < 8; kk++) aGO[kk] = ldg_frag(goR, it*16 + c15, 32*kk + 8*g);
  #pragma unroll 2
  for (int ct = 0; ct < 16; ct++){
    f32x4 acc{0,0,0,0};
    #pragma unroll
    for (int kk = 0; kk < 8; kk++)
      acc = mfma16(aGO[kk], ldg_frag(WoT, ct*16 + c15, 32*kk + 8*g), acc);
    const float bov = bo[ct*16 + c15];
    const int i0 = it*16 + g*4;
    const int cc = ct*16 + c15;
    out[(i0 + 0) * 65536 + r * 256 + cc] = acc.x + bov;
    out[(i0 + 1) * 65536 + r * 256 + cc] = acc.y + bov;
    out[(i0 + 2) * 65536 + r * 256 + cc] = acc.z + bov;
    out[(i0 + 3) * 65536 + r * 256 + cc] = acc.w + bov;
  }
}

// ================= fallback (round-4 kernel, proven correct) ===============
template<int IB>
__device__ __forceinline__ void attn_half_fb(
    const char* sm, const short* WqT, const short* WkT,
    const short* WvT, const short* WgT,
    int hbase, int g, int c15, float bg0, float bg1,
    unsigned (&go0)[8][2], unsigned (&go1)[8][2])
{
  const float scl = 0.17677669529663687f * 1.4426950408889634f;
  unsigned qTa[8][2], qTb[8][2];
  #pragma unroll
  for (int dr = 0; dr < 2; dr++){
    bf16x8 wq[8];
    #pragma unroll
    for (int kk = 0; kk < 8; kk++) wq[kk] = ldg_frag(WqT, hbase + 16*dr + c15, 32*kk + 8*g);
    #pragma unroll
    for (int nt = 0; nt < 8; nt++){
      f32x4 a{0,0,0,0};
      #pragma unroll
      for (int kk = 0; kk < 8; kk++)
        a = mfma16(wq[kk], lds_frag(sm, IB + nt*16 + c15, 32*kk + 8*g), a);
      if (dr == 0){ qTa[nt][0] = pk2(a.x*scl, a.y*scl); qTa[nt][1] = pk2(a.z*scl, a.w*scl); }
      else        { qTb[nt][0] = pk2(a.x*scl, a.y*scl); qTb[nt][1] = pk2(a.z*scl, a.w*scl); }
    }
  }
  float m_[8], l_[8];
  f32x4 o_[8][2];
  #pragma unroll
  for (int i2 = 0; i2 < 8; i2++){
    m_[i2] = -1e30f; l_[i2] = 0.f;
    o_[i2][0] = f32x4{0,0,0,0}; o_[i2][1] = f32x4{0,0,0,0};
  }
  #pragma unroll 1
  for (int jt = 0; jt < 8; jt++){
    const int jb = jt * 32;
    f32x4 kt00{0,0,0,0}, kt01{0,0,0,0}, kt10{0,0,0,0}, kt11{0,0,0,0};
    f32x4 va00{0,0,0,0}, va01{0,0,0,0}, va10{0,0,0,0}, va11{0,0,0,0};
    #pragma unroll
    for (int kk = 0; kk < 8; kk++){
      const int cs = 32*kk + 8*g;
      bf16x8 wk0 = ldg_frag(WkT, hbase + c15,      cs);
      bf16x8 wk1 = ldg_frag(WkT, hbase + 16 + c15, cs);
      bf16x8 wv0 = ldg_frag(WvT, hbase + c15,      cs);
      bf16x8 wv1 = ldg_frag(WvT, hbase + 16 + c15, cs);
      bf16x8 bx0 = lds_frag(sm, jb + c15,      cs);
      bf16x8 bx1 = lds_frag(sm, jb + 16 + c15, cs);
      kt00 = mfma16(wk0, bx0, kt00);
      kt01 = mfma16(wk0, bx1, kt01);
      kt10 = mfma16(wk1, bx0, kt10);
      kt11 = mfma16(wk1, bx1, kt11);
      va00 = mfma16(bx0, wv0, va00);
      va01 = mfma16(bx0, wv1, va01);
      va10 = mfma16(bx1, wv0, va10);
      va11 = mfma16(bx1, wv1, va11);
    }
    const bf16x8 kf0 = mk_frag(pk2(kt00.x,kt00.y), pk2(kt00.z,kt00.w),
                               pk2(kt10.x,kt10.y), pk2(kt10.z,kt10.w));
    const bf16x8 kf1 = mk_frag(pk2(kt01.x,kt01.y), pk2(kt01.z,kt01.w),
                               pk2(kt11.x,kt11.y), pk2(kt11.z,kt11.w));
    const bf16x8 vf0 = mk_frag(pk2(va00.x,va00.y), pk2(va00.z,va00.w),
                               pk2(va10.x,va10.y), pk2(va10.z,va10.w));
    const bf16x8 vf1 = mk_frag(pk2(va01.x,va01.y), pk2(va01.z,va01.w),
                               pk2(va11.x,va11.y), pk2(va11.z,va11.w));
    #pragma unroll
    for (int it = 0; it < 8; it++){
      bf16x8 bS = mk_frag(qTa[it][0], qTa[it][1], qTb[it][0], qTb[it][1]);
      f32x4 z{0,0,0,0};
      f32x4 s0 = mfma16(kf0, bS, z);
      f32x4 s1 = mfma16(kf1, bS, z);
      float pm = fmaxf(fmaxf(fmaxf(s0.x,s0.y), fmaxf(s0.z,s0.w)),
                       fmaxf(fmaxf(s1.x,s1.y), fmaxf(s1.z,s1.w)));
      pm = fmaxf(pm, __shfl_xor(pm, 16));
      pm = fmaxf(pm, __shfl_xor(pm, 32));
      const bool skip = __all(pm <= m_[it] + 8.f) != 0;
      const float mnew = skip ? m_[it] : fmaxf(m_[it], pm);
      float e0=exp2f(s0.x-mnew), e1=exp2f(s0.y-mnew), e2=exp2f(s0.z-mnew), e3=exp2f(s0.w-mnew);
      float e4=exp2f(s1.x-mnew), e5=exp2f(s1.y-mnew), e6=exp2f(s1.z-mnew), e7=exp2f(s1.w-mnew);
      float rs = ((e0+e1)+(e2+e3)) + ((e4+e5)+(e6+e7));
      rs += __shfl_xor(rs, 16); rs += __shfl_xor(rs, 32);
      if (skip){
        l_[it] += rs;
      } else {
        const float corr = exp2f(m_[it] - mnew);
        l_[it] = l_[it] * corr + rs;
        m_[it] = mnew;
        #pragma unroll
        for (int jj = 0; jj < 4; jj++){
          const float cj = __shfl(corr, 4*g + jj);
          o_[it][0][jj] *= cj;
          o_[it][1][jj] *= cj;
        }
      }
      bf16x8 aP = mk_frag(pk2(e0,e1), pk2(e2,e3), pk2(e4,e5), pk2(e6,e7));
      o_[it][0] = mfma16(aP, vf0, o_[it][0]);
      o_[it][1] = mfma16(aP, vf1, o_[it][1]);
    }
  }
  #pragma unroll
  for (int dr = 0; dr < 2; dr++){
    bf16x8 wg[8];
    #pragma unroll
    for (int kk = 0; kk < 8; kk++) wg[kk] = ldg_frag(WgT, hbase + 16*dr + c15, 32*kk + 8*g);
    const float bgd = dr ? bg1 : bg0;
    #pragma unroll
    for (int nt = 0; nt < 8; nt++){
      f32x4 a{0,0,0,0};
      #pragma unroll
      for (int kk = 0; kk < 8; kk++)
        a = mfma16(lds_frag(sm, IB + nt*16 + c15, 32*kk + 8*g), wg[kk], a);
      float inv[4];
      #pragma unroll
      for (int jj = 0; jj < 4; jj++) inv[jj] = 1.f / __shfl(l_[nt], 4*g + jj);
      const float ga0 = sigm(a.x + bgd), ga1 = sigm(a.y + bgd);
      const float ga2 = sigm(a.z + bgd), ga3 = sigm(a.w + bgd);
      const f32x4 ov = o_[nt][dr];
      const unsigned w0 = pk2(ov[0]*inv[0]*ga0, ov[1]*inv[1]*ga1);
      const unsigned w1 = pk2(ov[2]*inv[2]*ga2, ov[3]*inv[3]*ga3);
      if (dr == 0){ go0[nt][0] = w0; go0[nt][1] = w1; }
      else        { go1[nt][0] = w0; go1[nt][1] = w1; }
    }
  }
}

__device__ __forceinline__ void store_go(char* sm, int i0, int hd, unsigned v0, unsigned v1){
  *(short*)(sm + xaddr(i0 + 0, hd * 2)) = (short)(v0 & 0xffffu);
  *(short*)(sm + xaddr(i0 + 1, hd * 2)) = (short)(v0 >> 16);
  *(short*)(sm + xaddr(i0 + 2, hd * 2)) = (short)(v1 & 0xffffu);
  *(short*)(sm + xaddr(i0 + 3, hd * 2)) = (short)(v1 >> 16);
}

__global__ __launch_bounds__(512) __attribute__((amdgpu_waves_per_eu(2, 2)))
void msa_attn_fb(
    const float* __restrict__ msa, const float* __restrict__ lnw,
    const float* __restrict__ lnb, const float* __restrict__ bg,
    const float* __restrict__ bo,  const short* __restrict__ wsW,
    float* __restrict__ out)
{
  extern __shared__ __align__(16) char sm[];
  const int r   = blockIdx.x;
  const int tid = threadIdx.x;
  const float* msa_r = msa + r * 256;

  build_x_tile(sm, msa_r, lnw, lnb, tid);

  const int wid  = tid >> 6;
  const int lane = tid & 63;
  const int g = lane >> 4, c15 = lane & 15;
  const short* WqT = wsW;
  const short* WkT = wsW + 65536;
  const short* WvT = wsW + 2 * 65536;
  const short* WgT = wsW + 3 * 65536;
  const short* WoT = wsW + 4 * 65536;
  const int hbase = wid * 32;
  const float bg0 = bg[hbase + c15], bg1 = bg[hbase + 16 + c15];

  unsigned g00[8][2], g01[8][2], g10[8][2], g11[8][2];
  attn_half_fb<0>  (sm, WqT, WkT, WvT, WgT, hbase, g, c15, bg0, bg1, g00, g01);
  attn_half_fb<128>(sm, WqT, WkT, WvT, WgT, hbase, g, c15, bg0, bg1, g10, g11);

  __syncthreads();
  #pragma unroll
  for (int it = 0; it < 8; it++){
    const int ia = it * 16 + g * 4, ib = 128 + it * 16 + g * 4;
    store_go(sm, ia, hbase + c15,      g00[it][0], g00[it][1]);
    store_go(sm, ia, hbase + 16 + c15, g01[it][0], g01[it][1]);
    store_go(sm, ib, hbase + c15,      g10[it][0], g10[it][1]);
    store_go(sm, ib, hbase + 16 + c15, g11[it][0], g11[it][1]);
  }
  __syncthreads();

  #pragma unroll
  for (int t2 = 0; t2 < 2; t2++){
    const int it = wid * 2 + t2;
    bf16x8 aGO[8];
    #pragma unroll
    for (int kk = 0; kk < 8; kk++) aGO[kk] = lds_frag(sm, it * 16 + c15, 32 * kk + 8 * g);
    #pragma unroll 2
    for (int ct = 0; ct < 16; ct++){
      f32x4 acc{0,0,0,0};
      #pragma unroll
      for (int kk = 0; kk < 8; kk++)
        acc = mfma16(aGO[kk], ldg_frag(WoT, ct * 16 + c15, 32 * kk + 8 * g), acc);
      const float bov = bo[ct * 16 + c15];
      const int i0 = it * 16 + g * 4;
      const int cc = ct * 16 + c15;
      out[(i0 + 0) * 65536 + r * 256 + cc] = acc.x + bov;
      out[(i0 + 1) * 65536 + r * 256 + cc] = acc.y + bov;
      out[(i0 + 2) * 65536 + r * 256 + cc] = acc.z + bov;
      out[(i0 + 3) * 65536 + r * 256 + cc] = acc.w + bov;
    }
  }
}

// ---------------------------------------------------------------------------
extern "C" void kernel_launch(void* const* d_in, const int* in_sizes, int n_in,
                              void* d_out, int out_size, void* d_ws, size_t ws_size,
                              hipStream_t stream)
{
  (void)in_sizes; (void)n_in; (void)out_size;
  const float* msa = (const float*)d_in[0];
  const float* lnw = (const float*)d_in[1];
  const float* lnb = (const float*)d_in[2];
  const float* Wq  = (const float*)d_in[3];
  const float* Wk  = (const float*)d_in[4];
  const float* Wv  = (const float*)d_in[5];
  const float* Wg  = (const float*)d_in[6];
  const float* bg  = (const float*)d_in[7];
  const float* Wo  = (const float*)d_in[8];
  const float* bo  = (const float*)d_in[9];
  short* ws = (short*)d_ws;                    // weights 640 KB (+ GO 33.6 MB)

  prep_weights<<<256, 256, 0, stream>>>(Wq, Wk, Wv, Wg, Wo, ws);

  const size_t need = (size_t)(5 * 65536 + 256 * 65536) * sizeof(short); // 34.2 MB
  if (ws_size >= need){
    short* go = ws + 5 * 65536;
    msa_attn_go<<<256, 512, 133120, stream>>>(msa, lnw, lnb, bg, ws, go);
    out_proj<<<1024, 256, 0, stream>>>(go, ws + 4 * 65536, bo, (float*)d_out);
  } else {
    msa_attn_fb<<<256, 512, 133120, stream>>>(msa, lnw, lnb, bg, bo, ws, (float*)d_out);
  }
}

// Round 7
// 243.297 us; speedup vs baseline: 2.5492x; 1.0339x over previous
//
#include <hip/hip_runtime.h>
#include <hip/hip_bf16.h>

// B=1, S=256 (attention/LN axis), R=256, C=256, H=8, D=32.
// Round 7: round-6 AGPR-resident K/V plan + MANUAL MFMA HAZARD NOPS in the
// inline asm (the compiler's hazard recognizer cannot see into asm blobs:
// round 6's NaN). Each asm block: s_nop 1 before (VALU-write -> MFMA-read),
// and for QK^T (result read immediately by softmax VALU) s_nop 7 x2 after
// (MFMA-write-D -> VALU-read needs <=16 cycles on 4/8-pass XDL ops).
// K^T/V bf16 fragments (128 regs) live in AGPRs via "a" constraints, freeing
// the 128-arch-VGPR budget for flash-loop state -> no scratch spill.

using f32x4  = __attribute__((ext_vector_type(4))) float;
using bf16x8 = __attribute__((ext_vector_type(8))) short;

struct U4x { unsigned a0, a1, a2, a3; };
static_assert(sizeof(U4x) == sizeof(bf16x8), "frag size");

__device__ __forceinline__ f32x4 mfma16(bf16x8 a, bf16x8 b, f32x4 c){
  return __builtin_amdgcn_mfma_f32_16x16x32_bf16(a, b, c, 0, 0, 0);
}
// S^T pair: A operands from AGPR (K^T frags), B/C from VGPR. Results are
// consumed by VALU right after -> trailing 16 cycles of wait states.
__device__ __forceinline__ void mfma_ak2(f32x4& d0, f32x4& d1,
                                         bf16x8 a0, bf16x8 a1,
                                         bf16x8 b, f32x4 cz){
  asm("s_nop 1\n\t"
      "v_mfma_f32_16x16x32_bf16 %0, %2, %4, %5\n\t"
      "v_mfma_f32_16x16x32_bf16 %1, %3, %4, %5\n\t"
      "s_nop 7\n\t"
      "s_nop 7"
      : "=&v"(d0), "=&v"(d1)
      : "a"(a0), "a"(a1), "v"(b), "v"(cz));
}
// PV pair: B operands from AGPR (V frags), accumulate in place. D is not
// read by VALU for >=150 cycles (next rescale / finalize) -> no trailing nops.
__device__ __forceinline__ void mfma_pv2(f32x4& acc0, f32x4& acc1,
                                         bf16x8 ap, bf16x8 v0, bf16x8 v1){
  asm("s_nop 1\n\t"
      "v_mfma_f32_16x16x32_bf16 %0, %2, %3, %0\n\t"
      "v_mfma_f32_16x16x32_bf16 %1, %2, %4, %1"
      : "+v"(acc0), "+v"(acc1)
      : "v"(ap), "a"(v0), "a"(v1));
}
// f32 -> bf16 RNE, finite inputs only.
__device__ __forceinline__ unsigned f2bf(float f){
  unsigned u = __builtin_bit_cast(unsigned, f);
  u += 0x7fffu + ((u >> 16) & 1u);
  return u >> 16;
}
__device__ __forceinline__ unsigned pk2(float lo, float hi){
  return f2bf(lo) | (f2bf(hi) << 16);
}
__device__ __forceinline__ bf16x8 mk_frag(unsigned a0, unsigned a1, unsigned a2, unsigned a3){
  U4x t{a0, a1, a2, a3};
  return __builtin_bit_cast(bf16x8, t);
}
__device__ __forceinline__ float sigm(float x){ return 1.f / (1.f + __expf(-x)); }

// Swizzled byte address in the [256 rows][256 bf16] LDS tile (row stride 512B).
__device__ __forceinline__ int xaddr(int row, int cbyte){
  return (row << 9) + (cbyte ^ ((row & 15) << 4));
}
__device__ __forceinline__ bf16x8 lds_frag(const char* sm, int row, int cshort){
  return *(const bf16x8*)(sm + xaddr(row, cshort * 2));
}
__device__ __forceinline__ bf16x8 ldg_frag(const short* base, int row, int cshort){
  return *(const bf16x8*)(base + row * 256 + cshort);
}

// ---------------- prep: transpose + bf16-convert the 5 weight matrices -----
__global__ __launch_bounds__(256) void prep_weights(
    const float* __restrict__ Wq, const float* __restrict__ Wk,
    const float* __restrict__ Wv, const float* __restrict__ Wg,
    const float* __restrict__ Wo, short* __restrict__ ws)
{
  const int n = blockIdx.x, t = threadIdx.x;
  ws[0*65536 + n*256 + t] = (short)f2bf(Wq[t*256 + n]);
  ws[1*65536 + n*256 + t] = (short)f2bf(Wk[t*256 + n]);
  ws[2*65536 + n*256 + t] = (short)f2bf(Wv[t*256 + n]);
  ws[3*65536 + n*256 + t] = (short)f2bf(Wg[t*256 + n]);
  ws[4*65536 + n*256 + t] = (short)f2bf(Wo[t*256 + n]);
}

// ---------------- phase 1 (shared): LN stats + normalized x tile -----------
__device__ __forceinline__ void build_x_tile(
    char* sm, const float* msa_r, const float* lnw, const float* lnb, int tid)
{
  float* muA = (float*)(sm + 131072);
  float* rsA = muA + 256;
  {
    float s0 = 0.f, s1 = 0.f;
    const int c = tid & 255, sh = tid >> 8;
    const float* p = msa_r + (sh * 128) * 65536 + c;
    #pragma unroll 8
    for (int i = 0; i < 128; i++){ float v = p[i * 65536]; s0 += v; s1 += v * v; }
    float* sb = (float*)sm;
    sb[tid] = s0; sb[512 + tid] = s1;
    __syncthreads();
    if (tid < 256){
      float tot = sb[tid] + sb[256 + tid];
      float sq  = sb[512 + tid] + sb[768 + tid];
      float mu  = tot * (1.f / 256.f);
      float var = fmaxf(sq * (1.f / 256.f) - mu * mu, 0.f);
      muA[tid] = mu; rsA[tid] = rsqrtf(var + 1e-5f);
    }
    __syncthreads();
  }
  {
    const int c0 = (tid & 31) * 8;
    float mu0[8], rs0[8];
    #pragma unroll
    for (int k = 0; k < 8; k++){ mu0[k] = muA[c0 + k]; rs0[k] = rsA[c0 + k]; }
    for (int itr = 0; itr < 16; itr++){
      const int s = itr * 16 + (tid >> 5);
      const float w = lnw[s], b = lnb[s];
      const float* rp = msa_r + s * 65536 + c0;
      f32x4 v0 = *(const f32x4*)rp;
      f32x4 v1 = *(const f32x4*)(rp + 4);
      U4x q{pk2((v0.x-mu0[0])*rs0[0]*w+b, (v0.y-mu0[1])*rs0[1]*w+b),
            pk2((v0.z-mu0[2])*rs0[2]*w+b, (v0.w-mu0[3])*rs0[3]*w+b),
            pk2((v1.x-mu0[4])*rs0[4]*w+b, (v1.y-mu0[5])*rs0[5]*w+b),
            pk2((v1.z-mu0[6])*rs0[6]*w+b, (v1.w-mu0[7])*rs0[7]*w+b)};
      *(U4x*)(sm + xaddr(s, c0 * 2)) = q;
    }
    __syncthreads();
  }
}

// ---------------- main fused kernel (GO -> global scratch) -----------------
__global__ __launch_bounds__(512) __attribute__((amdgpu_waves_per_eu(2, 2)))
void msa_attn_go(
    const float* __restrict__ msa, const float* __restrict__ lnw,
    const float* __restrict__ lnb, const float* __restrict__ bg,
    const short* __restrict__ wsW, short* __restrict__ go)
{
  extern __shared__ __align__(16) char sm[];   // x tile (bf16, swizzled) + stats
  const int r   = blockIdx.x;
  const int tid = threadIdx.x;
  const float* msa_r = msa + r * 256;

  build_x_tile(sm, msa_r, lnw, lnb, tid);

  const int wid  = tid >> 6;                   // head
  const int lane = tid & 63;
  const int g = lane >> 4, c15 = lane & 15;
  const short* WqT = wsW;
  const short* WkT = wsW + 65536;
  const short* WvT = wsW + 2 * 65536;
  const short* WgT = wsW + 3 * 65536;
  const int hbase = wid * 32;
  const float bg0 = bg[hbase + c15], bg1 = bg[hbase + 16 + c15];
  // 1/sqrt(32) * log2(e): softmax in exp2 domain.
  const float scl = 0.17677669529663687f * 1.4426950408889634f;
  const f32x4 zz{0.f, 0.f, 0.f, 0.f};

  // ---- KV-gen ONCE; kfr/vfr live in AGPRs (only used via "a" asm) ----
  bf16x8 kfr[8][2], vfr[8][2];
  #pragma unroll
  for (int ch = 0; ch < 4; ch++){              // j-tile chunks of 2
    f32x4 kt[2][2][2], va[2][2][2];            // [j2][drow|jrow][jcol|dcol]
    #pragma unroll
    for (int a = 0; a < 2; a++)
      #pragma unroll
      for (int b = 0; b < 2; b++)
        #pragma unroll
        for (int d = 0; d < 2; d++){ kt[a][b][d] = zz; va[a][b][d] = zz; }
    #pragma unroll
    for (int kk = 0; kk < 8; kk++){
      const int cs = 32*kk + 8*g;
      bf16x8 wk0 = ldg_frag(WkT, hbase + c15,      cs);
      bf16x8 wk1 = ldg_frag(WkT, hbase + 16 + c15, cs);
      bf16x8 wv0 = ldg_frag(WvT, hbase + c15,      cs);
      bf16x8 wv1 = ldg_frag(WvT, hbase + 16 + c15, cs);
      #pragma unroll
      for (int j2 = 0; j2 < 2; j2++){
        const int jb = (ch*2 + j2) * 32;
        bf16x8 bx0 = lds_frag(sm, jb + c15,      cs);
        bf16x8 bx1 = lds_frag(sm, jb + 16 + c15, cs);
        kt[j2][0][0] = mfma16(wk0, bx0, kt[j2][0][0]);   // K^T[d 0:16 ][j 0:16 ]
        kt[j2][0][1] = mfma16(wk0, bx1, kt[j2][0][1]);   // K^T[d 0:16 ][j 16:32]
        kt[j2][1][0] = mfma16(wk1, bx0, kt[j2][1][0]);   // K^T[d 16:32][j 0:16 ]
        kt[j2][1][1] = mfma16(wk1, bx1, kt[j2][1][1]);   // K^T[d 16:32][j 16:32]
        va[j2][0][0] = mfma16(bx0, wv0, va[j2][0][0]);   // V[j 0:16 ][d 0:16 ]
        va[j2][0][1] = mfma16(bx0, wv1, va[j2][0][1]);   // V[j 0:16 ][d 16:32]
        va[j2][1][0] = mfma16(bx1, wv0, va[j2][1][0]);   // V[j 16:32][d 0:16 ]
        va[j2][1][1] = mfma16(bx1, wv1, va[j2][1][1]);   // V[j 16:32][d 16:32]
      }
    }
    #pragma unroll
    for (int j2 = 0; j2 < 2; j2++){
      const int jt = ch*2 + j2;
      kfr[jt][0] = mk_frag(pk2(kt[j2][0][0].x,kt[j2][0][0].y), pk2(kt[j2][0][0].z,kt[j2][0][0].w),
                           pk2(kt[j2][1][0].x,kt[j2][1][0].y), pk2(kt[j2][1][0].z,kt[j2][1][0].w));
      kfr[jt][1] = mk_frag(pk2(kt[j2][0][1].x,kt[j2][0][1].y), pk2(kt[j2][0][1].z,kt[j2][0][1].w),
                           pk2(kt[j2][1][1].x,kt[j2][1][1].y), pk2(kt[j2][1][1].z,kt[j2][1][1].w));
      vfr[jt][0] = mk_frag(pk2(va[j2][0][0].x,va[j2][0][0].y), pk2(va[j2][0][0].z,va[j2][0][0].w),
                           pk2(va[j2][1][0].x,va[j2][1][0].y), pk2(va[j2][1][0].z,va[j2][1][0].w));
      vfr[jt][1] = mk_frag(pk2(va[j2][0][1].x,va[j2][0][1].y), pk2(va[j2][0][1].z,va[j2][0][1].w),
                           pk2(va[j2][1][1].x,va[j2][1][1].y), pk2(va[j2][1][1].z,va[j2][1][1].w));
    }
  }

  // ---- 4 query chunks of 64 rows ----
  short* goR = go + r * 65536;
  #pragma unroll 1
  for (int chq = 0; chq < 4; chq++){
    const int ib = chq * 64;
    // A) Q^T for this chunk
    unsigned qTa[4][2], qTb[4][2];
    #pragma unroll
    for (int dr = 0; dr < 2; dr++){
      bf16x8 wq[8];
      #pragma unroll
      for (int kk = 0; kk < 8; kk++) wq[kk] = ldg_frag(WqT, hbase + 16*dr + c15, 32*kk + 8*g);
      #pragma unroll
      for (int nt = 0; nt < 4; nt++){
        f32x4 a{0,0,0,0};
        #pragma unroll
        for (int kk = 0; kk < 8; kk++)
          a = mfma16(wq[kk], lds_frag(sm, ib + nt*16 + c15, 32*kk + 8*g), a);
        if (dr == 0){ qTa[nt][0] = pk2(a.x*scl, a.y*scl); qTa[nt][1] = pk2(a.z*scl, a.w*scl); }
        else        { qTb[nt][0] = pk2(a.x*scl, a.y*scl); qTb[nt][1] = pk2(a.z*scl, a.w*scl); }
      }
    }
    // B) flash over j-tiles: pure-register (KV resident in AGPRs)
    float m_[4], l_[4];
    f32x4 o_[4][2];
    #pragma unroll
    for (int i2 = 0; i2 < 4; i2++){
      m_[i2] = -1e30f; l_[i2] = 0.f;
      o_[i2][0] = zz; o_[i2][1] = zz;
    }
    #pragma unroll
    for (int jt = 0; jt < 8; jt++){
      #pragma unroll
      for (int it = 0; it < 4; it++){
        bf16x8 bS = mk_frag(qTa[it][0], qTa[it][1], qTb[it][0], qTb[it][1]);
        f32x4 s0, s1;                       // S[i=c15][j=32jt+{4g+jj, 16+4g+jj}]
        mfma_ak2(s0, s1, kfr[jt][0], kfr[jt][1], bS, zz);
        float pm = fmaxf(fmaxf(fmaxf(s0.x,s0.y), fmaxf(s0.z,s0.w)),
                         fmaxf(fmaxf(s1.x,s1.y), fmaxf(s1.z,s1.w)));
        pm = fmaxf(pm, __shfl_xor(pm, 16));
        pm = fmaxf(pm, __shfl_xor(pm, 32));
        const bool skip = __all(pm <= m_[it] + 8.f) != 0;   // wave-uniform
        const float mnew = skip ? m_[it] : fmaxf(m_[it], pm);
        float e0=exp2f(s0.x-mnew), e1=exp2f(s0.y-mnew), e2=exp2f(s0.z-mnew), e3=exp2f(s0.w-mnew);
        float e4=exp2f(s1.x-mnew), e5=exp2f(s1.y-mnew), e6=exp2f(s1.z-mnew), e7=exp2f(s1.w-mnew);
        float rs = ((e0+e1)+(e2+e3)) + ((e4+e5)+(e6+e7));
        rs += __shfl_xor(rs, 16); rs += __shfl_xor(rs, 32);
        if (skip){
          l_[it] += rs;
        } else {
          const float corr = exp2f(m_[it] - mnew);
          l_[it] = l_[it] * corr + rs;
          m_[it] = mnew;
          #pragma unroll
          for (int jj = 0; jj < 4; jj++){
            const float cj = __shfl(corr, 4*g + jj);
            o_[it][0][jj] *= cj;
            o_[it][1][jj] *= cj;
          }
        }
        bf16x8 aP = mk_frag(pk2(e0,e1), pk2(e2,e3), pk2(e4,e5), pk2(e6,e7));
        mfma_pv2(o_[it][0], o_[it][1], aP, vfr[jt][0], vfr[jt][1]);
      }
    }
    // C) G = sigmoid(X@Wg+bg), normalize, gate, scatter GO (bf16) to global
    #pragma unroll
    for (int dr = 0; dr < 2; dr++){
      const float bgd = dr ? bg1 : bg0;
      #pragma unroll
      for (int nt = 0; nt < 4; nt++){
        f32x4 a{0,0,0,0};
        #pragma unroll
        for (int kk = 0; kk < 8; kk++)
          a = mfma16(lds_frag(sm, ib + nt*16 + c15, 32*kk + 8*g),
                     ldg_frag(WgT, hbase + 16*dr + c15, 32*kk + 8*g), a);
        float inv[4];
        #pragma unroll
        for (int jj = 0; jj < 4; jj++) inv[jj] = 1.f / __shfl(l_[nt], 4*g + jj);
        const float ga0 = sigm(a.x + bgd), ga1 = sigm(a.y + bgd);
        const float ga2 = sigm(a.z + bgd), ga3 = sigm(a.w + bgd);
        const f32x4 ov = o_[nt][dr];
        const unsigned w0 = pk2(ov[0]*inv[0]*ga0, ov[1]*inv[1]*ga1);
        const unsigned w1 = pk2(ov[2]*inv[2]*ga2, ov[3]*inv[3]*ga3);
        short* gp = goR + (ib + nt*16 + 4*g) * 256 + hbase + 16*dr + c15;
        gp[0]   = (short)(w0 & 0xffffu);
        gp[256] = (short)(w0 >> 16);
        gp[512] = (short)(w1 & 0xffffu);
        gp[768] = (short)(w1 >> 16);
      }
    }
  }
}

// ---------------- output projection: out = GO @ Wo + bo --------------------
__global__ __launch_bounds__(256) void out_proj(
    const short* __restrict__ go, const short* __restrict__ WoT,
    const float* __restrict__ bo, float* __restrict__ out)
{
  const int blk = blockIdx.x;            // 0..1023
  const int r = blk >> 2, chunk = blk & 3;
  const int wid = threadIdx.x >> 6, lane = threadIdx.x & 63;
  const int g = lane >> 4, c15 = lane & 15;
  const int it = chunk * 4 + wid;        // i-tile 0..15
  const short* goR = go + r * 65536;

  bf16x8 aGO[8];
  #pragma unroll
  for (int kk = 0; kk < 8; kk++) aGO[kk] = ldg_frag(goR, it*16 + c15, 32*kk + 8*g);
  #pragma unroll 2
  for (int ct = 0; ct < 16; ct++){
    f32x4 acc{0,0,0,0};
    #pragma unroll
    for (int kk = 0; kk < 8; kk++)
      acc = mfma16(aGO[kk], ldg_frag(WoT, ct*16 + c15, 32*kk + 8*g), acc);
    const float bov = bo[ct*16 + c15];
    const int i0 = it*16 + g*4;
    const int cc = ct*16 + c15;
    out[(i0 + 0) * 65536 + r * 256 + cc] = acc.x + bov;
    out[(i0 + 1) * 65536 + r * 256 + cc] = acc.y + bov;
    out[(i0 + 2) * 65536 + r * 256 + cc] = acc.z + bov;
    out[(i0 + 3) * 65536 + r * 256 + cc] = acc.w + bov;
  }
}

// ================= fallback (round-5 path, proven correct) =================
template<int IB>
__device__ __forceinline__ void attn_half_fb(
    const char* sm, const short* WqT, const short* WkT,
    const short* WvT, const short* WgT,
    int hbase, int g, int c15, float bg0, float bg1,
    unsigned (&go0)[8][2], unsigned (&go1)[8][2])
{
  const float scl = 0.17677669529663687f * 1.4426950408889634f;
  unsigned qTa[8][2], qTb[8][2];
  #pragma unroll
  for (int dr = 0; dr < 2; dr++){
    bf16x8 wq[8];
    #pragma unroll
    for (int kk = 0; kk < 8; kk++) wq[kk] = ldg_frag(WqT, hbase + 16*dr + c15, 32*kk + 8*g);
    #pragma unroll
    for (int nt = 0; nt < 8; nt++){
      f32x4 a{0,0,0,0};
      #pragma unroll
      for (int kk = 0; kk < 8; kk++)
        a = mfma16(wq[kk], lds_frag(sm, IB + nt*16 + c15, 32*kk + 8*g), a);
      if (dr == 0){ qTa[nt][0] = pk2(a.x*scl, a.y*scl); qTa[nt][1] = pk2(a.z*scl, a.w*scl); }
      else        { qTb[nt][0] = pk2(a.x*scl, a.y*scl); qTb[nt][1] = pk2(a.z*scl, a.w*scl); }
    }
  }
  float m_[8], l_[8];
  f32x4 o_[8][2];
  #pragma unroll
  for (int i2 = 0; i2 < 8; i2++){
    m_[i2] = -1e30f; l_[i2] = 0.f;
    o_[i2][0] = f32x4{0,0,0,0}; o_[i2][1] = f32x4{0,0,0,0};
  }
  #pragma unroll 1
  for (int jt = 0; jt < 8; jt++){
    const int jb = jt * 32;
    f32x4 kt00{0,0,0,0}, kt01{0,0,0,0}, kt10{0,0,0,0}, kt11{0,0,0,0};
    f32x4 va00{0,0,0,0}, va01{0,0,0,0}, va10{0,0,0,0}, va11{0,0,0,0};
    #pragma unroll
    for (int kk = 0; kk < 8; kk++){
      const int cs = 32*kk + 8*g;
      bf16x8 wk0 = ldg_frag(WkT, hbase + c15,      cs);
      bf16x8 wk1 = ldg_frag(WkT, hbase + 16 + c15, cs);
      bf16x8 wv0 = ldg_frag(WvT, hbase + c15,      cs);
      bf16x8 wv1 = ldg_frag(WvT, hbase + 16 + c15, cs);
      bf16x8 bx0 = lds_frag(sm, jb + c15,      cs);
      bf16x8 bx1 = lds_frag(sm, jb + 16 + c15, cs);
      kt00 = mfma16(wk0, bx0, kt00);
      kt01 = mfma16(wk0, bx1, kt01);
      kt10 = mfma16(wk1, bx0, kt10);
      kt11 = mfma16(wk1, bx1, kt11);
      va00 = mfma16(bx0, wv0, va00);
      va01 = mfma16(bx0, wv1, va01);
      va10 = mfma16(bx1, wv0, va10);
      va11 = mfma16(bx1, wv1, va11);
    }
    const bf16x8 kf0 = mk_frag(pk2(kt00.x,kt00.y), pk2(kt00.z,kt00.w),
                               pk2(kt10.x,kt10.y), pk2(kt10.z,kt10.w));
    const bf16x8 kf1 = mk_frag(pk2(kt01.x,kt01.y), pk2(kt01.z,kt01.w),
                               pk2(kt11.x,kt11.y), pk2(kt11.z,kt11.w));
    const bf16x8 vf0 = mk_frag(pk2(va00.x,va00.y), pk2(va00.z,va00.w),
                               pk2(va10.x,va10.y), pk2(va10.z,va10.w));
    const bf16x8 vf1 = mk_frag(pk2(va01.x,va01.y), pk2(va01.z,va01.w),
                               pk2(va11.x,va11.y), pk2(va11.z,va11.w));
    #pragma unroll
    for (int it = 0; it < 8; it++){
      bf16x8 bS = mk_frag(qTa[it][0], qTa[it][1], qTb[it][0], qTb[it][1]);
      f32x4 z{0,0,0,0};
      f32x4 s0 = mfma16(kf0, bS, z);
      f32x4 s1 = mfma16(kf1, bS, z);
      float pm = fmaxf(fmaxf(fmaxf(s0.x,s0.y), fmaxf(s0.z,s0.w)),
                       fmaxf(fmaxf(s1.x,s1.y), fmaxf(s1.z,s1.w)));
      pm = fmaxf(pm, __shfl_xor(pm, 16));
      pm = fmaxf(pm, __shfl_xor(pm, 32));
      const bool skip = __all(pm <= m_[it] + 8.f) != 0;
      const float mnew = skip ? m_[it] : fmaxf(m_[it], pm);
      float e0=exp2f(s0.x-mnew), e1=exp2f(s0.y-mnew), e2=exp2f(s0.z-mnew), e3=exp2f(s0.w-mnew);
      float e4=exp2f(s1.x-mnew), e5=exp2f(s1.y-mnew), e6=exp2f(s1.z-mnew), e7=exp2f(s1.w-mnew);
      float rs = ((e0+e1)+(e2+e3)) + ((e4+e5)+(e6+e7));
      rs += __shfl_xor(rs, 16); rs += __shfl_xor(rs, 32);
      if (skip){
        l_[it] += rs;
      } else {
        const float corr = exp2f(m_[it] - mnew);
        l_[it] = l_[it] * corr + rs;
        m_[it] = mnew;
        #pragma unroll
        for (int jj = 0; jj < 4; jj++){
          const float cj = __shfl(corr, 4*g + jj);
          o_[it][0][jj] *= cj;
          o_[it][1][jj] *= cj;
        }
      }
      bf16x8 aP = mk_frag(pk2(e0,e1), pk2(e2,e3), pk2(e4,e5), pk2(e6,e7));
      o_[it][0] = mfma16(aP, vf0, o_[it][0]);
      o_[it][1] = mfma16(aP, vf1, o_[it][1]);
    }
  }
  #pragma unroll
  for (int dr = 0; dr < 2; dr++){
    bf16x8 wg[8];
    #pragma unroll
    for (int kk = 0; kk < 8; kk++) wg[kk] = ldg_frag(WgT, hbase + 16*dr + c15, 32*kk + 8*g);
    const float bgd = dr ? bg1 : bg0;
    #pragma unroll
    for (int nt = 0; nt < 8; nt++){
      f32x4 a{0,0,0,0};
      #pragma unroll
      for (int kk = 0; kk < 8; kk++)
        a = mfma16(lds_frag(sm, IB + nt*16 + c15, 32*kk + 8*g), wg[kk], a);
      float inv[4];
      #pragma unroll
      for (int jj = 0; jj < 4; jj++) inv[jj] = 1.f / __shfl(l_[nt], 4*g + jj);
      const float ga0 = sigm(a.x + bgd), ga1 = sigm(a.y + bgd);
      const float ga2 = sigm(a.z + bgd), ga3 = sigm(a.w + bgd);
      const f32x4 ov = o_[nt][dr];
      const unsigned w0 = pk2(ov[0]*inv[0]*ga0, ov[1]*inv[1]*ga1);
      const unsigned w1 = pk2(ov[2]*inv[2]*ga2, ov[3]*inv[3]*ga3);
      if (dr == 0){ go0[nt][0] = w0; go0[nt][1] = w1; }
      else        { go1[nt][0] = w0; go1[nt][1] = w1; }
    }
  }
}

__device__ __forceinline__ void store_go(char* sm, int i0, int hd, unsigned v0, unsigned v1){
  *(short*)(sm + xaddr(i0 + 0, hd * 2)) = (short)(v0 & 0xffffu);
  *(short*)(sm + xaddr(i0 + 1, hd * 2)) = (short)(v0 >> 16);
  *(short*)(sm + xaddr(i0 + 2, hd * 2)) = (short)(v1 & 0xffffu);
  *(short*)(sm + xaddr(i0 + 3, hd * 2)) = (short)(v1 >> 16);
}

__global__ __launch_bounds__(512) __attribute__((amdgpu_waves_per_eu(2, 2)))
void msa_attn_fb(
    const float* __restrict__ msa, const float* __restrict__ lnw,
    const float* __restrict__ lnb, const float* __restrict__ bg,
    const float* __restrict__ bo,  const short* __restrict__ wsW,
    float* __restrict__ out)
{
  extern __shared__ __align__(16) char sm[];
  const int r   = blockIdx.x;
  const int tid = threadIdx.x;
  const float* msa_r = msa + r * 256;

  build_x_tile(sm, msa_r, lnw, lnb, tid);

  const int wid  = tid >> 6;
  const int lane = tid & 63;
  const int g = lane >> 4, c15 = lane & 15;
  const short* WqT = wsW;
  const short* WkT = wsW + 65536;
  const short* WvT = wsW + 2 * 65536;
  const short* WgT = wsW + 3 * 65536;
  const short* WoT = wsW + 4 * 65536;
  const int hbase = wid * 32;
  const float bg0 = bg[hbase + c15], bg1 = bg[hbase + 16 + c15];

  unsigned g00[8][2], g01[8][2], g10[8][2], g11[8][2];
  attn_half_fb<0>  (sm, WqT, WkT, WvT, WgT, hbase, g, c15, bg0, bg1, g00, g01);
  attn_half_fb<128>(sm, WqT, WkT, WvT, WgT, hbase, g, c15, bg0, bg1, g10, g11);

  __syncthreads();
  #pragma unroll
  for (int it = 0; it < 8; it++){
    const int ia = it * 16 + g * 4, ib = 128 + it * 16 + g * 4;
    store_go(sm, ia, hbase + c15,      g00[it][0], g00[it][1]);
    store_go(sm, ia, hbase + 16 + c15, g01[it][0], g01[it][1]);
    store_go(sm, ib, hbase + c15,      g10[it][0], g10[it][1]);
    store_go(sm, ib, hbase + 16 + c15, g11[it][0], g11[it][1]);
  }
  __syncthreads();

  #pragma unroll
  for (int t2 = 0; t2 < 2; t2++){
    const int it = wid * 2 + t2;
    bf16x8 aGO[8];
    #pragma unroll
    for (int kk = 0; kk < 8; kk++) aGO[kk] = lds_frag(sm, it * 16 + c15, 32 * kk + 8 * g);
    #pragma unroll 2
    for (int ct = 0; ct < 16; ct++){
      f32x4 acc{0,0,0,0};
      #pragma unroll
      for (int kk = 0; kk < 8; kk++)
        acc = mfma16(aGO[kk], ldg_frag(WoT, ct * 16 + c15, 32 * kk + 8 * g), acc);
      const float bov = bo[ct * 16 + c15];
      const int i0 = it * 16 + g * 4;
      const int cc = ct * 16 + c15;
      out[(i0 + 0) * 65536 + r * 256 + cc] = acc.x + bov;
      out[(i0 + 1) * 65536 + r * 256 + cc] = acc.y + bov;
      out[(i0 + 2) * 65536 + r * 256 + cc] = acc.z + bov;
      out[(i0 + 3) * 65536 + r * 256 + cc] = acc.w + bov;
    }
  }
}

// ---------------------------------------------------------------------------
extern "C" void kernel_launch(void* const* d_in, const int* in_sizes, int n_in,
                              void* d_out, int out_size, void* d_ws, size_t ws_size,
                              hipStream_t stream)
{
  (void)in_sizes; (void)n_in; (void)out_size;
  const float* msa = (const float*)d_in[0];
  const float* lnw = (const float*)d_in[1];
  const float* lnb = (const float*)d_in[2];
  const float* Wq  = (const float*)d_in[3];
  const float* Wk  = (const float*)d_in[4];
  const float* Wv  = (const float*)d_in[5];
  const float* Wg  = (const float*)d_in[6];
  const float* bg  = (const float*)d_in[7];
  const float* Wo  = (const float*)d_in[8];
  const float* bo  = (const float*)d_in[9];
  short* ws = (short*)d_ws;                    // weights 640 KB (+ GO 33.6 MB)

  prep_weights<<<256, 256, 0, stream>>>(Wq, Wk, Wv, Wg, Wo, ws);

  const size_t need = (size_t)(5 * 65536 + 256 * 65536) * sizeof(short); // 34.2 MB
  if (ws_size >= need){
    short* go = ws + 5 * 65536;
    msa_attn_go<<<256, 512, 133120, stream>>>(msa, lnw, lnb, bg, ws, go);
    out_proj<<<1024, 256, 0, stream>>>(go, ws + 4 * 65536, bo, (float*)d_out);
  } else {
    msa_attn_fb<<<256, 512, 133120, stream>>>(msa, lnw, lnb, bg, bo, ws, (float*)d_out);
  }
}